// Round 18
// baseline (479.101 us; speedup 1.0000x reference)
//
#include <hip/hip_runtime.h>

// ---- static configuration (mirrors reference) ----
#define N_SHOTS 8
#define NZP 304
#define NXP 304
#define NT 50
#define N_REC 300
#define FLAT (NZP * NXP)          // 92416
#define DT 0.001f
#define INV_DX 0.25f
#define INV_DX2 0.0625f

#define C23 (2.0f / 3.0f)
#define C112 (1.0f / 12.0f)
#define C43 (4.0f / 3.0f)

#define TPS 11552                 // 4x2 tasks per shot = 76 * 152

union F4 { float4 v; float f[4]; };
__device__ __forceinline__ F4 ldf4(const float* p) {
    F4 r; r.v = *reinterpret_cast<const float4*>(p); return r;
}
__device__ __forceinline__ F4 zf4() {
    F4 r; r.v = make_float4(0.f, 0.f, 0.f, 0.f); return r;
}

// One FDTD step. Each thread owns a 4(x) x 2(z) cell tile -> the z-column
// window loads (the VMEM bulk) are shared across both rows.
// State representation: pz/px arrays hold q = a*psi; zz/zx hold a*zeta
// (recurrences q' = (a*b)*d1 + a*q, azeta' = (a*b)*tmp + a*azeta) -> no
// neighbor a_z loads. PML profiles live in LDS (x-profiles as float4 ->
// conflict-free ds_read_b128). VMEM ~40/8cells vs R17's 60.
// Grid = 512 blocks = exactly 2/CU; shot = bid&7 pins shots to XCDs
// (R7-proven). Block j owns tasks [(j*TPS)>>6, ((j+1)*TPS)>>6) = 180/181.
// Receiver gather on lanes 187..191 (5/block * 60 blocks covers 300).
__global__ __launch_bounds__(192) void fdtd_stepq(
    const float* __restrict__ v,
    const float* __restrict__ amp,        // (NT, N_SHOTS, 1)
    const float* __restrict__ az, const float* __restrict__ bz, const float* __restrict__ dbz,
    const float* __restrict__ ax, const float* __restrict__ bx, const float* __restrict__ dbx,
    const int* __restrict__ src_i,
    const int* __restrict__ rec_i,
    const float* __restrict__ wc,         // current wavefield (read-only)
    float* __restrict__ wp,               // prev wavefield; overwritten with new
    const float* __restrict__ qzi, float* __restrict__ qzo,   // q_z = az*psi_z
    const float* __restrict__ qxi, float* __restrict__ qxo,   // q_x = ax*psi_x
    float* __restrict__ azz, float* __restrict__ azx,         // a*zeta (in place)
    float* __restrict__ rec_out,          // (NT, N_SHOTS, N_REC)
    int t)
{
    __shared__ float laz[NZP], lbz[NZP], ldbz[NZP];
    __shared__ float4 laxq[76], lbxq[76], ldbxq[76];

    const int tid = threadIdx.x;
    const int bid = blockIdx.x;
    const int shot = bid & 7;
    const int j = bid >> 3;               // 0..63
    const int sbase = shot * FLAT;

    // profile preload (all lanes participate)
    for (int p = tid; p < NZP; p += 192) {
        laz[p] = az[p]; lbz[p] = bz[p]; ldbz[p] = dbz[p];
    }
    if (tid < 76) {
        laxq[tid]  = *reinterpret_cast<const float4*>(ax + 4 * tid);
        lbxq[tid]  = *reinterpret_cast<const float4*>(bx + 4 * tid);
        ldbxq[tid] = *reinterpret_cast<const float4*>(dbx + 4 * tid);
    }
    __syncthreads();

    if (tid >= 187) {
        // receiver gather from pre-step wc (same shot -> same XCD)
        int ridx = j * 5 + (tid - 187);
        if (ridx < N_REC) {
            rec_out[t * (N_SHOTS * N_REC) + shot * N_REC + ridx] =
                wc[sbase + rec_i[shot * N_REC + ridx]];
        }
        return;
    }

    const int start = (j * TPS) >> 6;
    const int count = (((j + 1) * TPS) >> 6) - start;
    if (tid >= count) return;

    const int c = start + tid;            // task id in [0, TPS)
    const int m = c / 76;                 // z-pair index 0..151
    const int i = c - m * 76;             // x-chunk 0..75
    const int z0 = 2 * m;
    const int x0 = 4 * i;
    const int idx0 = sbase + z0 * NXP + x0;

    const int srci = src_i[shot];
    const float amp_t = amp[t * N_SHOTS + shot];

    // ---- z-column window: rows z0-2 .. z0+3 (wc and qz), guarded ----
    F4 wCw[6], qzw[6];
    #pragma unroll
    for (int r = 0; r < 6; ++r) {
        const int zr = z0 - 2 + r;
        const bool ok = (zr >= 0) && (zr < NZP);
        const int a = sbase + zr * NXP + x0;
        wCw[r] = ok ? ldf4(wc + a)  : zf4();
        qzw[r] = ok ? ldf4(qzi + a) : zf4();
    }

    // ---- x-neighbors for the two center rows ----
    const bool lok = (i > 0), rok = (i < 75);
    F4 wLr[2], wRr[2], qxL[2], qxC[2], qxR[2];
    F4 vR[2], wpR[2], azzR[2], azxR[2];
    #pragma unroll
    for (int r = 0; r < 2; ++r) {
        const int a = idx0 + r * NXP;
        wLr[r] = lok ? ldf4(wc + a - 4)  : zf4();
        wRr[r] = rok ? ldf4(wc + a + 4)  : zf4();
        qxC[r] = ldf4(qxi + a);
        qxL[r] = lok ? ldf4(qxi + a - 4) : zf4();
        qxR[r] = rok ? ldf4(qxi + a + 4) : zf4();
        vR[r]   = ldf4(v + (z0 + r) * NXP + x0);
        wpR[r]  = ldf4(wp + a);
        azzR[r] = ldf4(azz + a);
        azxR[r] = ldf4(azx + a);
    }

    const F4 axv = *(F4*)&laxq[i];
    const F4 bxv = *(F4*)&lbxq[i];
    const F4 dxv = *(F4*)&ldbxq[i];

    #pragma unroll
    for (int r = 0; r < 2; ++r) {
        const int z = z0 + r;
        const int idx = idx0 + r * NXP;
        const float azc = laz[z], bzc = lbz[z], dbzc = ldbz[z];
        const float azbz = azc * bzc;

        // 12-wide x windows for this row
        float wx[12], qxw[12];
        #pragma unroll
        for (int k = 0; k < 4; ++k) {
            wx[k]      = wLr[r].f[k];     qxw[k]     = qxL[r].f[k];
            wx[4 + k]  = wCw[2 + r].f[k]; qxw[4 + k] = qxC[r].f[k];
            wx[8 + k]  = wRr[r].f[k];     qxw[8 + k] = qxR[r].f[k];
        }

        F4 o_w, o_qz, o_qx, o_zz, o_zx;
        #pragma unroll
        for (int k = 0; k < 4; ++k) {
            const float cc = wx[4 + k];
            const float d1x  = ((wx[5 + k] - wx[3 + k]) * C23 + (wx[2 + k] - wx[6 + k]) * C112) * INV_DX;
            const float d2x  = (-2.5f * cc + C43 * (wx[5 + k] + wx[3 + k]) - C112 * (wx[6 + k] + wx[2 + k])) * INV_DX2;
            const float dapx = ((qxw[5 + k] - qxw[3 + k]) * C23 + (qxw[2 + k] - qxw[6 + k]) * C112) * INV_DX;

            const float d1z  = ((wCw[3 + r].f[k] - wCw[1 + r].f[k]) * C23 + (wCw[r].f[k] - wCw[4 + r].f[k]) * C112) * INV_DX;
            const float d2z  = (-2.5f * cc + C43 * (wCw[3 + r].f[k] + wCw[1 + r].f[k]) - C112 * (wCw[4 + r].f[k] + wCw[r].f[k])) * INV_DX2;
            const float dapz = ((qzw[3 + r].f[k] - qzw[1 + r].f[k]) * C23 + (qzw[r].f[k] - qzw[4 + r].f[k]) * C112) * INV_DX;

            const float tmpz = (1.f + bzc) * d2z + dbzc * d1z + dapz;
            float w_sum = (1.f + bzc) * tmpz + azzR[r].f[k];

            const float bxk = bxv.f[k], axk = axv.f[k];
            const float tmpx = (1.f + bxk) * d2x + dxv.f[k] * d1x + dapx;
            w_sum += (1.f + bxk) * tmpx + azxR[r].f[k];

            const float vv = vR[r].f[k];
            float wn = (vv * vv) * (DT * DT) * w_sum + 2.f * cc - wpR[r].f[k];
            if (z * NXP + x0 + k == srci) wn += amp_t;

            o_w.f[k]  = wn;
            o_qz.f[k] = azbz * d1z + azc * qzw[2 + r].f[k];
            o_qx.f[k] = (axk * bxk) * d1x + axk * qxC[r].f[k];
            o_zz.f[k] = azbz * tmpz + azc * azzR[r].f[k];
            o_zx.f[k] = (axk * bxk) * tmpx + axk * azxR[r].f[k];
        }

        *reinterpret_cast<float4*>(wp + idx)  = o_w.v;
        *reinterpret_cast<float4*>(qzo + idx) = o_qz.v;
        *reinterpret_cast<float4*>(qxo + idx) = o_qx.v;
        *reinterpret_cast<float4*>(azz + idx) = o_zz.v;
        *reinterpret_cast<float4*>(azx + idx) = o_zx.v;
    }
}

extern "C" void kernel_launch(void* const* d_in, const int* in_sizes, int n_in,
                              void* d_out, int out_size, void* d_ws, size_t ws_size,
                              hipStream_t stream) {
    const float* v     = (const float*)d_in[0];
    const float* amp   = (const float*)d_in[1];
    const float* az    = (const float*)d_in[2];
    const float* bz    = (const float*)d_in[3];
    const float* dbz   = (const float*)d_in[4];
    const float* ax    = (const float*)d_in[5];
    const float* bx    = (const float*)d_in[6];
    const float* dbx   = (const float*)d_in[7];
    const int* src_i   = (const int*)d_in[8];
    const int* rec_i   = (const int*)d_in[9];
    float* out = (float*)d_out;

    float* ws = (float*)d_ws;
    const size_t A = (size_t)N_SHOTS * FLAT;

    // Layout: [wf0, wf1, qz0, qx0, azz, azx | qz1, qx1] — first 6 zeroed;
    // qz1/qx1 fully written at t=0 before being read.
    float* wf0 = ws + 0 * A; float* wf1 = ws + 1 * A;
    float* qz0 = ws + 2 * A; float* qx0 = ws + 3 * A;
    float* azz = ws + 4 * A; float* azx = ws + 5 * A;
    float* qz1 = ws + 6 * A; float* qx1 = ws + 7 * A;

    hipMemsetAsync(d_ws, 0, 6 * A * sizeof(float), stream);

    float* wf[2] = { wf0, wf1 };
    float* qz[2] = { qz0, qz1 };
    float* qx[2] = { qx0, qx1 };

    int cur = 0;
    for (int t = 0; t < NT; ++t) {
        fdtd_stepq<<<512, 192, 0, stream>>>(
            v, amp, az, bz, dbz, ax, bx, dbx, src_i, rec_i,
            wf[cur], wf[1 - cur],
            qz[cur], qz[1 - cur],
            qx[cur], qx[1 - cur],
            azz, azx, out, t);
        cur ^= 1;
    }
}